// Round 14
// baseline (2032.929 us; speedup 1.0000x reference)
//
#include <hip/hip_runtime.h>

#define L_PAD 8192
#define HS    25
#define ES    50
#define G4    100   // 4*H
#define CHUNK 64    // z-staging chunk (steps); 64*50 float2 = 25600 B = 25 lds-DMA instrs
#define LOG2E 1.44269504088896340736f

// -------- workspace layout --------
// zs2   : float2[2][L_PAD*50]   packed gate preacts, PRE-SCALED for exp2:
//         zs2[d][t*50+j] = ( (z[j])*(-LOG2E), (z[j+50])*sy(j) )
//         sy(j) = -2*LOG2E for j<25 (tanh gate), -LOG2E otherwise (sigmoid)
// wstar : float2[2][50]         h* @ Wh, same (scaled) packing
// cstar : float [2][25]         frozen cell state (unscaled)

typedef _Float16 h2 __attribute__((ext_vector_type(2)));

__device__ __forceinline__ float fast_tanh(float x) {
    // 2*sigmoid(2x) - 1
    return fmaf(__builtin_amdgcn_rcpf(1.f + __builtin_amdgcn_exp2f(x * (-2.f * LOG2E))), 2.f, -1.f);
}
// sigmoid of a PRE-SCALED argument X = x*(-LOG2E)
__device__ __forceinline__ float sig_pre(float X) {
    return __builtin_amdgcn_rcpf(1.f + __builtin_amdgcn_exp2f(X));
}

// lane l gets its partner's value from lane l^32 (VALU permlane) — R5-verified semantics:
//   r[0]: lanes<32 = own, lanes>=32 = partner;  r[1]: lanes<32 = partner, lanes>=32 = own
__device__ __forceinline__ float xswap32(float v, bool hi) {
#if __has_builtin(__builtin_amdgcn_permlane32_swap)
    auto r = __builtin_amdgcn_permlane32_swap(__float_as_uint(v), __float_as_uint(v),
                                              false, false);
    return __uint_as_float(hi ? r[0] : r[1]);
#else
    return __int_as_float(__builtin_amdgcn_ds_bpermute(
        (int)(((threadIdx.x ^ 32u) & 63u) << 2), __float_as_int(v)));
#endif
}

// fp16-pair dot with fp32 accumulate: products exact in fp32, acc fp32 (RNE).
__device__ __forceinline__ float fdot2u(unsigned au, unsigned bu, float c) {
#if __has_builtin(__builtin_amdgcn_fdot2)
    return __builtin_amdgcn_fdot2(__builtin_bit_cast(h2, au),
                                  __builtin_bit_cast(h2, bu), c, false);
#else
    h2 a = __builtin_bit_cast(h2, au), b = __builtin_bit_cast(h2, bu);
    return fmaf((float)a.x, (float)b.x, fmaf((float)a.y, (float)b.y, c));
#endif
}

// ---------------- kernel 1: pre-activations (parallel) ----------------
__global__ __launch_bounds__(64) void k_pre(
    const int* __restrict__ tok, const int* __restrict__ plen,
    const float* __restrict__ Ef, const float* __restrict__ Wif, const float* __restrict__ bf,
    const float* __restrict__ Eb, const float* __restrict__ Wib, const float* __restrict__ bb,
    float2* __restrict__ zs2)
{
    const int b = blockIdx.x;
    const int d = b & 1;
    const int t = b >> 1;
    const int j = threadIdx.x;
    const int len = *plen;

    int src;
    if (d == 0) src = t;
    else        src = (t < len) ? (len - 1 - t) : (L_PAD - 1 - (t - len));
    const int token = tok[src];

    const float* __restrict__ E  = d ? Eb  : Ef;
    const float* __restrict__ Wi = d ? Wib : Wif;
    const float* __restrict__ bs = d ? bb  : bf;

    __shared__ float e[ES];
    if (j < ES) e[j] = E[(size_t)token * ES + j];
    __syncthreads();
    if (j >= 50) return;

    float ax = bs[j], ay = bs[j + 50];
    float bx = 0.f,  by = 0.f;
    #pragma unroll
    for (int k = 0; k < ES; k += 2) {
        float e0 = e[k], e1 = e[k + 1];
        ax = fmaf(e0, Wi[k * G4 + j],            ax);
        ay = fmaf(e0, Wi[k * G4 + j + 50],       ay);
        bx = fmaf(e1, Wi[(k + 1) * G4 + j],      bx);
        by = fmaf(e1, Wi[(k + 1) * G4 + j + 50], by);
    }
    // pre-scale for exp2: x-gates (i/f) sigmoid -> -LOG2E; y-gates: g(tanh) -> -2LOG2E, o -> -LOG2E
    const float sy = (j < 25) ? (-2.f * LOG2E) : (-LOG2E);
    zs2[(size_t)d * (L_PAD * 50) + t * 50 + j] =
        make_float2((ax + bx) * (-LOG2E), (ay + by) * sy);
}

// ---------------- kernel 2: the serial recurrence (latency-bound) ----------------
// R13 flat (-0.3%): the binding path is the ~180-cyc LDS write->read broadcast
// turnaround, not VALU trimming. Round-14 theory: R6/R7's readlane path lost
// ~350 cyc/step NOT to irreducible SGPR hazards but to the scheduler
// INTERLEAVING readlane->pack->dot adjacently (~25 cyc waitstates x13 pairs).
// Fix: CLUSTER the broadcast — cvt, then sched_barrier(0), all 25 v_readlane
// + 13 uniform packs (SALU pipe), sched_barrier(0), then all 26 dots. Hazards
// self-space inside the cluster; phase ~70 cyc vs LDS trip ~180. Arithmetic
// bit-identical to R13 (same h16 bits, same pack layout, u12 hi zeroed).
// Everything else = R13 verified structure.
__global__ __launch_bounds__(64, 1)
void k_seq(
    const float* __restrict__ Whf, const float* __restrict__ Whb,
    const int* __restrict__ plen,
    const float2* __restrict__ zs2_all,
    float* __restrict__ out,
    float2* __restrict__ wstar, float* __restrict__ cstar)
{
    __shared__ float4 zch[2][CHUNK * 25];    // double-buffered z chunks: 2 x 25600 B
    __shared__ float  obuf[2][CHUNK * 25];   // double-buffered out accum:  2 x 6400 B

    const int d = blockIdx.x;
    const int l = threadIdx.x;
    const int len = *plen;
    const float* __restrict__ Wh = d ? Whb : Whf;
    const bool hi32 = (l >= 32);
    const bool act = (l < 25) || (l >= 32 && l < 57);
    // col ownership: lanes 0..24 -> p=l (i,g); lanes 32..56 -> p=l-7 (f,o);
    // idle 25..31 -> p=l, idle 57..63 -> p=l-32 (duplicate real cols)
    const int p = (l < 32) ? l : ((l < 57) ? (l - 7) : (l - 32));

    // branch-free activation constants: y-gate is tanh for lanes<32 (g), sigmoid else (o)
    const float my_ = hi32 ? (-LOG2E) : (-2.f * LOG2E);
    const float ca = hi32 ? 1.f : 2.f;
    const float cb = hi32 ? 0.f : -1.f;

    // ---- weights: 26 fp16x2 regs (k-pairs), PRE-SCALED, loaded once, laundered ----
    unsigned wxu[13], wyu[13];
    {
        const float* __restrict__ Wc = Wh + p;
        #pragma unroll
        for (int kk = 0; kk < 13; ++kk) {
            float a0 = Wc[(2 * kk) * G4] * (-LOG2E);
            float b0 = Wc[(2 * kk) * G4 + 50] * my_;
            float a1 = 0.f, b1 = 0.f;
            if (kk < 12) {
                a1 = Wc[(2 * kk + 1) * G4] * (-LOG2E);
                b1 = Wc[(2 * kk + 1) * G4 + 50] * my_;
            }
            h2 wa; wa.x = (_Float16)a0; wa.y = (_Float16)a1;   // RNE cvt
            h2 wb; wb.x = (_Float16)b0; wb.y = (_Float16)b1;
            wxu[kk] = __builtin_bit_cast(unsigned, wa);
            wyu[kk] = __builtin_bit_cast(unsigned, wb);
            asm volatile("" : "+v"(wxu[kk]), "+v"(wyu[kk]));
        }
    }

    const float4* __restrict__ zf4 = (const float4*)(zs2_all + (size_t)d * (L_PAD * 50));

    float c = 0.f, h = 0.f;   // all lanes bounded forever (sigmoid/tanh outputs)

    #define STAGE(BUF, CI)                                                              \
        {                                                                               \
            const float4* gsrc = zf4 + (size_t)(CI) * (CHUNK * 25) + l;                 \
            _Pragma("unroll")                                                           \
            for (int i = 0; i < 25; ++i) {                                              \
                __builtin_amdgcn_global_load_lds(                                       \
                    (const __attribute__((address_space(1))) unsigned int*)(gsrc + 64 * i), \
                    (__attribute__((address_space(3))) unsigned int*)(&zch[BUF][i * 64]),   \
                    16, 0, 0);                                                          \
            }                                                                           \
        }

    // clustered-readlane h-broadcast: cvt -> [fence] 25 readlane + 13 packs
    // [fence] -> dots. readlane ignores EXEC (all lanes hold h16i). Packs are
    // uniform-int ops (SALU pipe, parallel to VALU). u12 hi explicitly 0.
    unsigned u0, u1, u2, u3, u4, u5, u6, u7, u8, u9, u10, u11, u12;
    #define RL(K) __builtin_amdgcn_readlane(h16i, K)
    #define PKU(A, B) (((unsigned)(A) & 0xffffu) | ((unsigned)(B) << 16))
    #define EMIT_H(HV)                                                                   \
        {                                                                                \
            int h16i = (int)(unsigned)__builtin_bit_cast(unsigned short, (_Float16)(HV));\
            __builtin_amdgcn_sched_barrier(0);                                           \
            int r0  = RL(0),  r1  = RL(1),  r2  = RL(2),  r3  = RL(3),  r4  = RL(4);     \
            int r5  = RL(5),  r6  = RL(6),  r7  = RL(7),  r8  = RL(8),  r9  = RL(9);     \
            int r10 = RL(10), r11 = RL(11), r12 = RL(12), r13 = RL(13), r14 = RL(14);    \
            int r15 = RL(15), r16 = RL(16), r17 = RL(17), r18 = RL(18), r19 = RL(19);    \
            int r20 = RL(20), r21 = RL(21), r22 = RL(22), r23 = RL(23), r24 = RL(24);    \
            u0  = PKU(r0,  r1);  u1  = PKU(r2,  r3);  u2  = PKU(r4,  r5);                \
            u3  = PKU(r6,  r7);  u4  = PKU(r8,  r9);  u5  = PKU(r10, r11);               \
            u6  = PKU(r12, r13); u7  = PKU(r14, r15); u8  = PKU(r16, r17);               \
            u9  = PKU(r18, r19); u10 = PKU(r20, r21); u11 = PKU(r22, r23);               \
            u12 = (unsigned)r24 & 0xffffu;                                               \
            __builtin_amdgcn_sched_barrier(0);                                           \
        }
    #define DD(KK, X, Y) X = fdot2u(wxu[KK], u##KK, X); Y = fdot2u(wyu[KK], u##KK, Y);

    const int nch = (len + CHUNK - 1) / CHUNK;
    int buf = 0, ob = 0;
    if (nch > 0) {
        STAGE(0, 0)
        asm volatile("s_waitcnt vmcnt(0)" ::: "memory");
        __builtin_amdgcn_sched_barrier(0);
    }
    EMIT_H(h)   // pipeline fill: broadcast of h=0

    for (int ct = 0; ct < nch; ++ct) {
        if (ct + 1 < L_PAD / CHUNK) STAGE(buf ^ 1, ct + 1)   // prefetch next chunk (no wait)

        const int t0 = ct * CHUNK;
        const int ne = (len - t0 < CHUNK) ? (len - t0) : CHUNK;
        const float2* __restrict__ zc = (const float2*)zch[buf];

        float2 ztc = zc[p];                   // z for step 0 of this chunk
        #pragma unroll 2
        for (int s = 0; s < ne; ++s) {
            int sn = (s + 1 < CHUNK) ? (s + 1) : s;
            float2 ztn = zc[sn * 50 + p];     // prefetch next step's z (h-independent)

            float x0 = ztc.x, x1 = 0.f, x2 = 0.f;
            float y0 = ztc.y, y1 = 0.f, y2 = 0.f;
            DD(0, x0, y0)  DD(1, x1, y1)  DD(2, x2, y2)
            DD(3, x0, y0)  DD(4, x1, y1)  DD(5, x2, y2)
            DD(6, x0, y0)  DD(7, x1, y1)  DD(8, x2, y2)
            DD(9, x0, y0)  DD(10, x1, y1) DD(11, x2, y2)
            DD(12, x0, y0)
            float px = (x0 + x1) + x2;        // already exp2-scaled
            float py = (y0 + y1) + y2;

            float sa = sig_pre(px);               // i (lanes<32) / f (lanes>=32)
            float ry = sig_pre(py);
            float sb = fmaf(ry, ca, cb);          // g=tanh (lanes<32) / o=sigmoid
            float f_ = xswap32(sa, hi32);
            float o_ = xswap32(sb, hi32);
            float nc = fmaf(f_, c, sa * sb);      // f*c + i*g
            float nh = o_ * fast_tanh(nc);
            c = nc;
            h = nh;
            EMIT_H(nh)                            // next step's broadcast (no LDS trip)
            if (l < 25) obuf[ob][s * 25 + l] = nh;   // LDS only — no VMEM in this loop
            ztc = ztn;
        }

        // staged loads for chunk ct+1 (and chunk ct-1's flush stores) are long done
        asm volatile("s_waitcnt vmcnt(0)" ::: "memory");
        __builtin_amdgcn_sched_barrier(0);

        // bulk-flush obuf[ob] -> out (fire-and-forget; drained at next chunk boundary)
        {
            const int E = ne * 25;
            #pragma unroll
            for (int it = 0; it < 25; ++it) {
                int e = l + 64 * it;
                if (e < E) {
                    int s_ = e / 25;
                    int j_ = e - 25 * s_;
                    out[(t0 + s_) * 50 + d * HS + j_] = obuf[ob][e];
                }
            }
        }
        ob ^= 1;
        buf ^= 1;
    }

    // epilogue: w* = h* @ Wh (scaled convention, consumed by k_tail) — u* already
    // hold the final h (issued by the last EMIT_H); c* for the frozen tail
    {
        float x0 = 0.f, x1 = 0.f, x2 = 0.f;
        float y0 = 0.f, y1 = 0.f, y2 = 0.f;
        DD(0, x0, y0)  DD(1, x1, y1)  DD(2, x2, y2)
        DD(3, x0, y0)  DD(4, x1, y1)  DD(5, x2, y2)
        DD(6, x0, y0)  DD(7, x1, y1)  DD(8, x2, y2)
        DD(9, x0, y0)  DD(10, x1, y1) DD(11, x2, y2)
        DD(12, x0, y0)
        if (act)    wstar[d * 50 + p] = make_float2((x0 + x1) + x2, (y0 + y1) + y2);
        if (l < 25) cstar[d * HS + l] = c;
    }
}

// ---------------- kernel 3: frozen-carry tail (parallel) ----------------
// consumes the SCALED z/wstar convention: exp2 args are already scaled.
__global__ __launch_bounds__(256) void k_tail(
    const int* __restrict__ plen,
    const float2* __restrict__ zs2_all,
    const float2* __restrict__ wstar, const float* __restrict__ cstar,
    float* __restrict__ out)
{
    const int tid = blockIdx.x * 256 + threadIdx.x;
    if (tid >= L_PAD * 50) return;
    const int col = tid % 50;
    const int t   = tid / 50;
    const int len = *plen;
    if (t < len) return;
    const int d = col / HS;
    const int j = col % HS;

    const float2* __restrict__ z = zs2_all + (size_t)d * (L_PAD * 50);
    float2 zi = z[t * 50 + j];
    float2 zq = z[t * 50 + j + 25];
    float2 wi = wstar[d * 50 + j];
    float2 wq = wstar[d * 50 + j + 25];

    float i_ = sig_pre(zi.x + wi.x);
    float g_ = fmaf(sig_pre(zi.y + wi.y), 2.f, -1.f);   // tanh, pre-scaled arg
    float f_ = sig_pre(zq.x + wq.x);
    float o_ = sig_pre(zq.y + wq.y);

    float nc = fmaf(f_, cstar[d * HS + j], i_ * g_);
    out[t * 50 + col] = o_ * fast_tanh(nc);
}

extern "C" void kernel_launch(void* const* d_in, const int* in_sizes, int n_in,
                              void* d_out, int out_size, void* d_ws, size_t ws_size,
                              hipStream_t stream)
{
    const int*   tok  = (const int*)  d_in[0];
    const int*   plen = (const int*)  d_in[1];
    const float* Ef   = (const float*)d_in[2];
    const float* Wif  = (const float*)d_in[3];
    const float* Whf  = (const float*)d_in[4];
    const float* bf   = (const float*)d_in[5];
    const float* Eb   = (const float*)d_in[6];
    const float* Wib  = (const float*)d_in[7];
    const float* Whb  = (const float*)d_in[8];
    const float* bb   = (const float*)d_in[9];
    float* out = (float*)d_out;

    float2* zs2   = (float2*)d_ws;
    float2* wstar = (float2*)((char*)d_ws + (size_t)2 * L_PAD * 50 * sizeof(float2));
    float*  cstar = (float*)((char*)wstar + 100 * sizeof(float2));

    k_pre <<<2 * L_PAD, 64, 0, stream>>>(tok, plen, Ef, Wif, bf, Eb, Wib, bb, zs2);
    k_seq <<<2, 64, 0, stream>>>(Whf, Whb, plen, zs2, out, wstar, cstar);
    k_tail<<<(L_PAD * 50 + 255) / 256, 256, 0, stream>>>(plen, zs2, wstar, cstar, out);
}

// Round 15
// 1378.351 us; speedup vs baseline: 1.4749x; 1.4749x over previous
//
#include <hip/hip_runtime.h>

#define L_PAD 8192
#define HS    25
#define ES    50
#define G4    100   // 4*H
#define CHUNK 64    // z-staging chunk (steps); 64*50 float2 = 25600 B = 25 lds-DMA instrs
#define LOG2E 1.44269504088896340736f

// -------- workspace layout --------
// zs2   : float2[2][L_PAD*50]   packed gate preacts, PRE-SCALED for exp2:
//         zs2[d][t*50+j] = ( (z[j])*(-LOG2E), (z[j+50])*sy(j) )
//         sy(j) = -2*LOG2E for j<25 (tanh gate), -LOG2E otherwise (sigmoid)
// wstar : float2[2][50]         h* @ Wh, same (scaled) packing
// cstar : float [2][25]         frozen cell state (unscaled)
//
// Session ledger (k_seq): R0 2003us (scratch-spilled weights, SGPR-hazard
// readlane gather) -> R9 1432 (VGPR/crossbar gather: SGPR hazards were ~350
// cyc/step) -> R11 1283 (one-buffer LDS broadcast + TBAA fix) -> R13 1279.7
// (exp2 pre-scaling) = BEST VERIFIED. Falsified: R12 DPP (2/2 container
// kills), R14 clustered readlane (1950us: SGPR-read hazard is per-op and
// scheduler-irreducible). This file = R13 verbatim.

typedef _Float16 h2 __attribute__((ext_vector_type(2)));
typedef int4 i4a __attribute__((may_alias));
typedef int  ia  __attribute__((may_alias));

__device__ __forceinline__ float fast_tanh(float x) {
    // 2*sigmoid(2x) - 1
    return fmaf(__builtin_amdgcn_rcpf(1.f + __builtin_amdgcn_exp2f(x * (-2.f * LOG2E))), 2.f, -1.f);
}
// sigmoid of a PRE-SCALED argument X = x*(-LOG2E)
__device__ __forceinline__ float sig_pre(float X) {
    return __builtin_amdgcn_rcpf(1.f + __builtin_amdgcn_exp2f(X));
}

// lane l gets its partner's value from lane l^32 (VALU permlane) — R5-verified semantics:
//   r[0]: lanes<32 = own, lanes>=32 = partner;  r[1]: lanes<32 = partner, lanes>=32 = own
__device__ __forceinline__ float xswap32(float v, bool hi) {
#if __has_builtin(__builtin_amdgcn_permlane32_swap)
    auto r = __builtin_amdgcn_permlane32_swap(__float_as_uint(v), __float_as_uint(v),
                                              false, false);
    return __uint_as_float(hi ? r[0] : r[1]);
#else
    return __int_as_float(__builtin_amdgcn_ds_bpermute(
        (int)(((threadIdx.x ^ 32u) & 63u) << 2), __float_as_int(v)));
#endif
}

// fp16-pair dot with fp32 accumulate: products exact in fp32, acc fp32 (RNE).
__device__ __forceinline__ float fdot2u(unsigned au, unsigned bu, float c) {
#if __has_builtin(__builtin_amdgcn_fdot2)
    return __builtin_amdgcn_fdot2(__builtin_bit_cast(h2, au),
                                  __builtin_bit_cast(h2, bu), c, false);
#else
    h2 a = __builtin_bit_cast(h2, au), b = __builtin_bit_cast(h2, bu);
    return fmaf((float)a.x, (float)b.x, fmaf((float)a.y, (float)b.y, c));
#endif
}

// ---------------- kernel 1: pre-activations (parallel) ----------------
__global__ __launch_bounds__(64) void k_pre(
    const int* __restrict__ tok, const int* __restrict__ plen,
    const float* __restrict__ Ef, const float* __restrict__ Wif, const float* __restrict__ bf,
    const float* __restrict__ Eb, const float* __restrict__ Wib, const float* __restrict__ bb,
    float2* __restrict__ zs2)
{
    const int b = blockIdx.x;
    const int d = b & 1;
    const int t = b >> 1;
    const int j = threadIdx.x;
    const int len = *plen;

    int src;
    if (d == 0) src = t;
    else        src = (t < len) ? (len - 1 - t) : (L_PAD - 1 - (t - len));
    const int token = tok[src];

    const float* __restrict__ E  = d ? Eb  : Ef;
    const float* __restrict__ Wi = d ? Wib : Wif;
    const float* __restrict__ bs = d ? bb  : bf;

    __shared__ float e[ES];
    if (j < ES) e[j] = E[(size_t)token * ES + j];
    __syncthreads();
    if (j >= 50) return;

    float ax = bs[j], ay = bs[j + 50];
    float bx = 0.f,  by = 0.f;
    #pragma unroll
    for (int k = 0; k < ES; k += 2) {
        float e0 = e[k], e1 = e[k + 1];
        ax = fmaf(e0, Wi[k * G4 + j],            ax);
        ay = fmaf(e0, Wi[k * G4 + j + 50],       ay);
        bx = fmaf(e1, Wi[(k + 1) * G4 + j],      bx);
        by = fmaf(e1, Wi[(k + 1) * G4 + j + 50], by);
    }
    // pre-scale for exp2: x-gates (i/f) sigmoid -> -LOG2E; y-gates: g(tanh) -> -2LOG2E, o -> -LOG2E
    const float sy = (j < 25) ? (-2.f * LOG2E) : (-LOG2E);
    zs2[(size_t)d * (L_PAD * 50) + t * 50 + j] =
        make_float2((ax + bx) * (-LOG2E), (ay + by) * sy);
}

// ---------------- kernel 2: the serial recurrence (latency-bound) ----------------
// Best verified structure (R13): chunked global_load_lds z-staging (one vmcnt
// per 64 steps), LDS out-buffer + per-chunk bulk flush (zero VMEM in the step
// loop), reg-resident pre-scaled fp16x2 weights + v_dot2_f32_f16 matvec,
// one-buffer LDS-crossbar h-broadcast (ds_write_b16 + 3x ds_read_b128 + b32
// at wave-uniform addresses; may_alias + asm memory fence pin the RAW order),
// permlane32_swap gate exchange, exp2 pre-scaling folded into z and weights.
__global__ __launch_bounds__(64, 1)
void k_seq(
    const float* __restrict__ Whf, const float* __restrict__ Whb,
    const int* __restrict__ plen,
    const float2* __restrict__ zs2_all,
    float* __restrict__ out,
    float2* __restrict__ wstar, float* __restrict__ cstar)
{
    __shared__ float4 zch[2][CHUNK * 25];    // double-buffered z chunks: 2 x 25600 B
    __shared__ float  obuf[2][CHUNK * 25];   // double-buffered out accum:  2 x 6400 B
    __shared__ __attribute__((aligned(16))) unsigned short hb[64];  // h16 broadcast (128 B)

    const int d = blockIdx.x;
    const int l = threadIdx.x;
    const int len = *plen;
    const float* __restrict__ Wh = d ? Whb : Whf;
    const bool hi32 = (l >= 32);
    const bool act = (l < 25) || (l >= 32 && l < 57);
    // col ownership: lanes 0..24 -> p=l (i,g); lanes 32..56 -> p=l-7 (f,o);
    // idle 25..31 -> p=l, idle 57..63 -> p=l-32 (duplicate real cols)
    const int p = (l < 32) ? l : ((l < 57) ? (l - 7) : (l - 32));

    // branch-free activation constants: y-gate is tanh for lanes<32 (g), sigmoid else (o)
    const float my_ = hi32 ? (-LOG2E) : (-2.f * LOG2E);
    const float ca = hi32 ? 1.f : 2.f;
    const float cb = hi32 ? 0.f : -1.f;

    // ---- weights: 26 fp16x2 regs (k-pairs), PRE-SCALED, loaded once, laundered ----
    unsigned wxu[13], wyu[13];
    {
        const float* __restrict__ Wc = Wh + p;
        #pragma unroll
        for (int kk = 0; kk < 13; ++kk) {
            float a0 = Wc[(2 * kk) * G4] * (-LOG2E);
            float b0 = Wc[(2 * kk) * G4 + 50] * my_;
            float a1 = 0.f, b1 = 0.f;
            if (kk < 12) {
                a1 = Wc[(2 * kk + 1) * G4] * (-LOG2E);
                b1 = Wc[(2 * kk + 1) * G4 + 50] * my_;
            }
            h2 wa; wa.x = (_Float16)a0; wa.y = (_Float16)a1;   // RNE cvt
            h2 wb; wb.x = (_Float16)b0; wb.y = (_Float16)b1;
            wxu[kk] = __builtin_bit_cast(unsigned, wa);
            wyu[kk] = __builtin_bit_cast(unsigned, wb);
            asm volatile("" : "+v"(wxu[kk]), "+v"(wyu[kk]));
        }
    }

    const float4* __restrict__ zf4 = (const float4*)(zs2_all + (size_t)d * (L_PAD * 50));

    float c = 0.f, h = 0.f;   // all lanes bounded forever (sigmoid/tanh outputs)

    #define STAGE(BUF, CI)                                                              \
        {                                                                               \
            const float4* gsrc = zf4 + (size_t)(CI) * (CHUNK * 25) + l;                 \
            _Pragma("unroll")                                                           \
            for (int i = 0; i < 25; ++i) {                                              \
                __builtin_amdgcn_global_load_lds(                                       \
                    (const __attribute__((address_space(1))) unsigned int*)(gsrc + 64 * i), \
                    (__attribute__((address_space(3))) unsigned int*)(&zch[BUF][i * 64]),   \
                    16, 0, 0);                                                          \
            }                                                                           \
        }

    // one-buffer h-broadcast (R11-verified): write own fp16, fence (compiler
    // order), read 13 packed dwords at uniform addresses. Issued at the end of
    // a step; u* consumed at the start of the next step.
    unsigned u0, u1, u2, u3, u4, u5, u6, u7, u8, u9, u10, u11, u12;
    #define EMIT_H(HV)                                                                   \
        {                                                                                \
            hb[l] = __builtin_bit_cast(unsigned short, (_Float16)(HV));                  \
            asm volatile("" ::: "memory");   /* pin read-after-write program order */    \
            const i4a* hb4 = (const i4a*)hb;                                             \
            int4 ra = hb4[0];                                                            \
            int4 rb = hb4[1];                                                            \
            int4 rc = hb4[2];                                                            \
            int  rd = ((const ia*)hb)[12];                                               \
            u0 = (unsigned)ra.x;  u1 = (unsigned)ra.y;  u2  = (unsigned)ra.z;            \
            u3 = (unsigned)ra.w;  u4 = (unsigned)rb.x;  u5  = (unsigned)rb.y;            \
            u6 = (unsigned)rb.z;  u7 = (unsigned)rb.w;  u8  = (unsigned)rc.x;            \
            u9 = (unsigned)rc.y;  u10 = (unsigned)rc.z; u11 = (unsigned)rc.w;            \
            u12 = (unsigned)rd;                                                          \
        }
    #define DD(KK, X, Y) X = fdot2u(wxu[KK], u##KK, X); Y = fdot2u(wyu[KK], u##KK, Y);

    const int nch = (len + CHUNK - 1) / CHUNK;
    int buf = 0, ob = 0;
    if (nch > 0) {
        STAGE(0, 0)
        asm volatile("s_waitcnt vmcnt(0)" ::: "memory");
        __builtin_amdgcn_sched_barrier(0);
    }
    EMIT_H(h)   // pipeline fill: broadcast of h=0

    for (int ct = 0; ct < nch; ++ct) {
        if (ct + 1 < L_PAD / CHUNK) STAGE(buf ^ 1, ct + 1)   // prefetch next chunk (no wait)

        const int t0 = ct * CHUNK;
        const int ne = (len - t0 < CHUNK) ? (len - t0) : CHUNK;
        const float2* __restrict__ zc = (const float2*)zch[buf];

        float2 ztc = zc[p];                   // z for step 0 of this chunk
        #pragma unroll 2
        for (int s = 0; s < ne; ++s) {
            int sn = (s + 1 < CHUNK) ? (s + 1) : s;
            float2 ztn = zc[sn * 50 + p];     // prefetch next step's z (h-independent)

            float x0 = ztc.x, x1 = 0.f, x2 = 0.f;
            float y0 = ztc.y, y1 = 0.f, y2 = 0.f;
            DD(0, x0, y0)  DD(1, x1, y1)  DD(2, x2, y2)
            DD(3, x0, y0)  DD(4, x1, y1)  DD(5, x2, y2)
            DD(6, x0, y0)  DD(7, x1, y1)  DD(8, x2, y2)
            DD(9, x0, y0)  DD(10, x1, y1) DD(11, x2, y2)
            DD(12, x0, y0)
            float px = (x0 + x1) + x2;        // already exp2-scaled
            float py = (y0 + y1) + y2;

            float sa = sig_pre(px);               // i (lanes<32) / f (lanes>=32)
            float ry = sig_pre(py);
            float sb = fmaf(ry, ca, cb);          // g=tanh (lanes<32) / o=sigmoid
            float f_ = xswap32(sa, hi32);
            float o_ = xswap32(sb, hi32);
            float nc = fmaf(f_, c, sa * sb);      // f*c + i*g
            float nh = o_ * fast_tanh(nc);
            c = nc;
            h = nh;
            EMIT_H(nh)                            // next step's broadcast
            if (l < 25) obuf[ob][s * 25 + l] = nh;   // LDS only — no VMEM in this loop
            ztc = ztn;
        }

        // staged loads for chunk ct+1 (and chunk ct-1's flush stores) are long done
        asm volatile("s_waitcnt vmcnt(0)" ::: "memory");
        __builtin_amdgcn_sched_barrier(0);

        // bulk-flush obuf[ob] -> out (fire-and-forget; drained at next chunk boundary)
        {
            const int E = ne * 25;
            #pragma unroll
            for (int it = 0; it < 25; ++it) {
                int e = l + 64 * it;
                if (e < E) {
                    int s_ = e / 25;
                    int j_ = e - 25 * s_;
                    out[(t0 + s_) * 50 + d * HS + j_] = obuf[ob][e];
                }
            }
        }
        ob ^= 1;
        buf ^= 1;
    }

    // epilogue: w* = h* @ Wh (scaled convention, consumed by k_tail) — u* already
    // hold the final h (issued by the last EMIT_H); c* for the frozen tail
    {
        float x0 = 0.f, x1 = 0.f, x2 = 0.f;
        float y0 = 0.f, y1 = 0.f, y2 = 0.f;
        DD(0, x0, y0)  DD(1, x1, y1)  DD(2, x2, y2)
        DD(3, x0, y0)  DD(4, x1, y1)  DD(5, x2, y2)
        DD(6, x0, y0)  DD(7, x1, y1)  DD(8, x2, y2)
        DD(9, x0, y0)  DD(10, x1, y1) DD(11, x2, y2)
        DD(12, x0, y0)
        if (act)    wstar[d * 50 + p] = make_float2((x0 + x1) + x2, (y0 + y1) + y2);
        if (l < 25) cstar[d * HS + l] = c;
    }
}

// ---------------- kernel 3: frozen-carry tail (parallel) ----------------
// consumes the SCALED z/wstar convention: exp2 args are already scaled.
__global__ __launch_bounds__(256) void k_tail(
    const int* __restrict__ plen,
    const float2* __restrict__ zs2_all,
    const float2* __restrict__ wstar, const float* __restrict__ cstar,
    float* __restrict__ out)
{
    const int tid = blockIdx.x * 256 + threadIdx.x;
    if (tid >= L_PAD * 50) return;
    const int col = tid % 50;
    const int t   = tid / 50;
    const int len = *plen;
    if (t < len) return;
    const int d = col / HS;
    const int j = col % HS;

    const float2* __restrict__ z = zs2_all + (size_t)d * (L_PAD * 50);
    float2 zi = z[t * 50 + j];
    float2 zq = z[t * 50 + j + 25];
    float2 wi = wstar[d * 50 + j];
    float2 wq = wstar[d * 50 + j + 25];

    float i_ = sig_pre(zi.x + wi.x);
    float g_ = fmaf(sig_pre(zi.y + wi.y), 2.f, -1.f);   // tanh, pre-scaled arg
    float f_ = sig_pre(zq.x + wq.x);
    float o_ = sig_pre(zq.y + wq.y);

    float nc = fmaf(f_, cstar[d * HS + j], i_ * g_);
    out[t * 50 + col] = o_ * fast_tanh(nc);
}

extern "C" void kernel_launch(void* const* d_in, const int* in_sizes, int n_in,
                              void* d_out, int out_size, void* d_ws, size_t ws_size,
                              hipStream_t stream)
{
    const int*   tok  = (const int*)  d_in[0];
    const int*   plen = (const int*)  d_in[1];
    const float* Ef   = (const float*)d_in[2];
    const float* Wif  = (const float*)d_in[3];
    const float* Whf  = (const float*)d_in[4];
    const float* bf   = (const float*)d_in[5];
    const float* Eb   = (const float*)d_in[6];
    const float* Wib  = (const float*)d_in[7];
    const float* Whb  = (const float*)d_in[8];
    const float* bb   = (const float*)d_in[9];
    float* out = (float*)d_out;

    float2* zs2   = (float2*)d_ws;
    float2* wstar = (float2*)((char*)d_ws + (size_t)2 * L_PAD * 50 * sizeof(float2));
    float*  cstar = (float*)((char*)wstar + 100 * sizeof(float2));

    k_pre <<<2 * L_PAD, 64, 0, stream>>>(tok, plen, Ef, Wif, bf, Eb, Wib, bb, zs2);
    k_seq <<<2, 64, 0, stream>>>(Whf, Whb, plen, zs2, out, wstar, cstar);
    k_tail<<<(L_PAD * 50 + 255) / 256, 256, 0, stream>>>(plen, zs2, wstar, cstar, out);
}